// Round 8
// baseline (14330.592 us; speedup 1.0000x reference)
//
#include <hip/hip_runtime.h>
#include <math.h>

// Problem constants
#define NB   16
#define CC   256
#define NPTS 16384       // 16*32*32
#define KK   8192
#define Z_OUT 4194304    // NPTS*CC
// d_out: [0,Z_OUT) z_q_out (BCHW), [Z_OUT,Z_OUT+NPTS) idx as float, [Z_OUT+NPTS] loss
// d_out scratch reuse: zT fp32[16384][256] fills the z_q region until k_gather
// overwrites it (rescore reads zT, writes idx — disjoint regions).

// ws layout (float-slot offsets)
#define WS_ZNORM  64
#define WS_ENORM  16448
#define WS_SETMAX 24640          // float[16384][128]  (2,097,152 slots, 8 MB)
#define WS_ZB16   2121792        // bf16[16384][256]   (1,048,576 float-slots)
#define WS_EBF    3170368        // bf16[8192][256]    (524,288 float-slots)
#define MARGIN    4.0e-4f        // >= 2*bf16 dot err + d-quantum + enorm spread (proof r8)

typedef short v8s __attribute__((ext_vector_type(8)));
typedef float v4f __attribute__((ext_vector_type(4)));

__device__ __forceinline__ void gl_lds16(const void* g, void* l) {
    __builtin_amdgcn_global_load_lds((const __attribute__((address_space(1))) void*)g,
                                     (__attribute__((address_space(3))) void*)l, 16, 0, 0);
}
__device__ __forceinline__ unsigned short f2bf(float f) {   // RNE, finite inputs
    unsigned int u = __float_as_uint(f);
    return (unsigned short)((u + 0x7FFFu + ((u >> 16) & 1u)) >> 16);
}
__device__ __forceinline__ float bfv(unsigned short u) {
    return __uint_as_float((unsigned int)u << 16);
}

// ---------------- P0: z BCHW fp32 -> zT[n][c] fp32 (d_out) + zb16[n][c] bf16 --------
__global__ void k_prep_z(const float* __restrict__ z, float* __restrict__ zT,
                         unsigned short* __restrict__ zb16) {
    __shared__ float ts[64][65];
    const int hw0 = blockIdx.x * 64, c0 = blockIdx.y * 64, b = blockIdx.z;
    const int tid = threadIdx.x;
#pragma unroll
    for (int p = 0; p < 4; ++p) {
        int u = p * 256 + tid;
        int ci = u >> 4, j4 = (u & 15) << 2;
        float4 v = *(const float4*)(z + (size_t)b * 262144 + (size_t)(c0 + ci) * 1024 + hw0 + j4);
        ts[ci][j4 + 0] = v.x; ts[ci][j4 + 1] = v.y; ts[ci][j4 + 2] = v.z; ts[ci][j4 + 3] = v.w;
    }
    __syncthreads();
#pragma unroll
    for (int p = 0; p < 4; ++p) {
        int u = p * 256 + tid;
        int hj = u >> 4, i4 = (u & 15) << 2;
        const size_t row = (size_t)(b * 1024 + hw0 + hj) * 256 + c0 + i4;
        float4 f = make_float4(ts[i4 + 0][hj], ts[i4 + 1][hj], ts[i4 + 2][hj], ts[i4 + 3][hj]);
        *(float4*)(zT + row) = f;
        *(ushort4*)(zb16 + row) = make_ushort4(f2bf(f.x), f2bf(f.y), f2bf(f.z), f2bf(f.w));
    }
}

// ---------------- P1: emb fp32 -> ebf[k][c] bf16 ----------------
__global__ void k_prep_e(const float* __restrict__ emb, unsigned short* __restrict__ ebf) {
    const int i = (blockIdx.x * 256 + threadIdx.x) * 8;
    float4 a = *(const float4*)(emb + i);
    float4 b = *(const float4*)(emb + i + 4);
    *(ushort4*)(ebf + i)     = make_ushort4(f2bf(a.x), f2bf(a.y), f2bf(a.z), f2bf(a.w));
    *(ushort4*)(ebf + i + 4) = make_ushort4(f2bf(b.x), f2bf(b.y), f2bf(b.z), f2bf(b.w));
}

// ---------------- znorm + zero loss ----------------
__global__ void k_znorm(const float* __restrict__ z, float* __restrict__ znorm,
                        float* __restrict__ lossAcc) {
    const int n  = blockIdx.x * 256 + threadIdx.x;
    const int b  = n >> 10, hw = n & 1023;
    const float* p = z + (size_t)b * 262144 + hw;
    float s = 0.0f;
#pragma unroll 8
    for (int c = 0; c < CC; ++c) {
        float v = p[(size_t)c * 1024];
        s = fmaf(v, v, s);
    }
    znorm[n] = s;
    if (n == 0) lossAcc[0] = 0.0f;
}

// ---------------- enorm ----------------
__global__ void k_enorm(const float* __restrict__ emb, float* __restrict__ enorm) {
    const int w = threadIdx.x >> 6, lane = threadIdx.x & 63;
    const int k = blockIdx.x * 4 + w;
    float4 v = *(const float4*)(emb + (size_t)k * CC + lane * 4);
    float s = v.x * v.x + v.y * v.y + v.z * v.z + v.w * v.w;
    for (int off = 32; off > 0; off >>= 1) s += __shfl_down(s, off);
    if (lane == 0) enorm[k] = s;
}

// ---------------- Phase 1: bf16 MFMA dots -> per-64k-set column maxima -------------
// 256 blocks x 512 thr (8 waves, 2 blk/CU @ 72 KB LDS). Block = 64 n, all 8192 k.
// Wave w owns k [w*1024,(w+1)*1024) = global sets w*16..w*16+15 (64 k each).
// Epilogue per set: register max + 2 shfl + 4 stores — no barriers, no atomics.
// mfma_f32_16x16x32_bf16 D: col(n)=lane&15, row(k)=(lane>>4)*4+reg (verified r5-7).
__global__ __launch_bounds__(512)
void k_phase1(const unsigned short* __restrict__ zb16, const unsigned short* __restrict__ ebf,
              float* __restrict__ setmax) {
    __shared__ short As[2][8][4][512];   // 64 KB  [buf][wave][ktile][lane*8]
    __shared__ short Bs[2][4][512];      // 8 KB   [buf][ntile][lane*8]

    const int tid  = threadIdx.x;
    const int lane = tid & 63;
    const int w    = tid >> 6;
    const int nb   = blockIdx.x << 6;
    const int m16  = lane & 15, q = lane >> 4;

    auto stage = [&](int t) {
        const int s = t >> 3, c0 = (t & 7) << 5, buf = t & 1;
        const int kbase = (w << 10) + (s << 6);
#pragma unroll
        for (int kt = 0; kt < 4; ++kt) {
            const unsigned short* g = ebf + (size_t)(kbase + (kt << 4) + m16) * 256 + c0 + q * 8;
            gl_lds16(g, &As[buf][w][kt][lane * 8]);
        }
        if (w < 4) {
            const unsigned short* g = zb16 + (size_t)(nb + (w << 4) + m16) * 256 + c0 + q * 8;
            gl_lds16(g, &Bs[buf][w][lane * 8]);
        }
    };

    stage(0);

    v4f acc[16];
#pragma unroll
    for (int i = 0; i < 16; ++i) acc[i] = (v4f){0.f, 0.f, 0.f, 0.f};

#pragma unroll 1
    for (int t = 0; t < 128; ++t) {
        __syncthreads();
        if (t + 1 < 128) stage(t + 1);
        const int buf = t & 1;
        v8s af[4], bf[4];
#pragma unroll
        for (int kt = 0; kt < 4; ++kt) af[kt] = *(const v8s*)&As[buf][w][kt][lane * 8];
#pragma unroll
        for (int nt = 0; nt < 4; ++nt) bf[nt] = *(const v8s*)&Bs[buf][nt][lane * 8];
#pragma unroll
        for (int kt = 0; kt < 4; ++kt)
#pragma unroll
            for (int nt = 0; nt < 4; ++nt)
                acc[kt * 4 + nt] = __builtin_amdgcn_mfma_f32_16x16x32_bf16(
                    af[kt], bf[nt], acc[kt * 4 + nt], 0, 0, 0);

        if ((t & 7) == 7) {   // end of 64-k set: write column maxima
            const int s = t >> 3;
#pragma unroll
            for (int nt = 0; nt < 4; ++nt) {
                float m = acc[nt][0];
#pragma unroll
                for (int kt = 0; kt < 4; ++kt)
#pragma unroll
                    for (int r = 0; r < 4; ++r) m = fmaxf(m, acc[kt * 4 + nt][r]);
                m = fmaxf(m, __shfl_xor(m, 16));
                m = fmaxf(m, __shfl_xor(m, 32));   // col max for n = nb+nt*16+m16
                if (q == 0)
                    setmax[(size_t)(nb + nt * 16 + m16) * 128 + (w << 4) + s] = m;
            }
#pragma unroll
            for (int i = 0; i < 16; ++i) acc[i] = (v4f){0.f, 0.f, 0.f, 0.f};
        }
    }
}

// ---------------- Phase 2: set-filter + bf16 VALU rescan + exact fp32 rescore ------
// One wave per row (4096 blocks x 256 thr). thr = true global bf-dot max - MARGIN.
// Superset proof (r8): dot'(k*) >= gmax - 2.1e-4 > gmax - MARGIN for any summation
// order of the identical bf16 products; winner's set passes the set filter likewise.
__global__ __launch_bounds__(256)
void k_rescore(const float* __restrict__ zT, const float* __restrict__ emb,
               const unsigned short* __restrict__ zb16, const unsigned short* __restrict__ ebf,
               const float* __restrict__ znorm, const float* __restrict__ enorm,
               const float* __restrict__ setmax, float* __restrict__ idx_out) {
    const int lane = threadIdx.x & 63;
    const int n    = blockIdx.x * 4 + (threadIdx.x >> 6);

    const float s0 = setmax[(size_t)n * 128 + lane];
    const float s1 = setmax[(size_t)n * 128 + 64 + lane];
    float gm = fmaxf(s0, s1);
#pragma unroll
    for (int off = 1; off < 64; off <<= 1) gm = fmaxf(gm, __shfl_xor(gm, off));
    const float thr = gm - MARGIN;

    unsigned long long q0 = __ballot(s0 >= thr);
    unsigned long long q1 = __ballot(s1 >= thr);

    const unsigned short* zb = zb16 + (size_t)n * CC;
    const float* zp = zT + (size_t)n * CC;
    const float zn = znorm[n];

    float bd = __builtin_inff();
    int   bk = 0x7fffffff;

    auto do_set = [&](int s) {
        const int k = s * 64 + lane;
        const unsigned short* eb = ebf + (size_t)k * CC;
        float a = 0.0f;
#pragma unroll 8
        for (int c = 0; c < CC; c += 4) {
            const ushort4 zu = *(const ushort4*)(zb + c);
            const ushort4 eu = *(const ushort4*)(eb + c);
            a = fmaf(bfv(zu.x), bfv(eu.x), a);
            a = fmaf(bfv(zu.y), bfv(eu.y), a);
            a = fmaf(bfv(zu.z), bfv(eu.z), a);
            a = fmaf(bfv(zu.w), bfv(eu.w), a);
        }
        if (a >= thr) {   // second filter; exact chain identical to round-4/5
            const float* ep = emb + (size_t)k * CC;
            float e = 0.0f;
#pragma unroll 8
            for (int c4 = 0; c4 < CC / 4; ++c4) {
                const float4 zv = *(const float4*)(zp + c4 * 4);
                const float4 ev = *(const float4*)(ep + c4 * 4);
                e = fmaf(zv.x, ev.x, e);
                e = fmaf(zv.y, ev.y, e);
                e = fmaf(zv.z, ev.z, e);
                e = fmaf(zv.w, ev.w, e);
            }
            const float tt = zn + enorm[k];
            const float d = tt - (e + e);
            if (d < bd || (d == bd && k < bk)) { bd = d; bk = k; }
        }
    };

    while (q0) { int s = __builtin_ctzll(q0); q0 &= q0 - 1; do_set(s); }
    while (q1) { int s = __builtin_ctzll(q1); q1 &= q1 - 1; do_set(64 + s); }

    // cross-lane min with smaller-k tie-break
#pragma unroll
    for (int off = 32; off > 0; off >>= 1) {
        const float od = __shfl_down(bd, off);
        const int   ok = __shfl_down(bk, off);
        if (od < bd || (od == bd && ok < bk)) { bd = od; bk = ok; }
    }
    if (lane == 0) idx_out[n] = (float)bk;
}

// ---------------- gather z_q (BCHW, coalesced) + loss partials ----------------
__global__ void k_gather(const float* __restrict__ z, const float* __restrict__ emb,
                         const float* __restrict__ idxf, float* __restrict__ out,
                         float* __restrict__ lossAcc) {
    __shared__ int   kis[1024];
    __shared__ float red[256];
    const int b = blockIdx.x, cg = blockIdx.y;   // 16 x 16
    const int t = threadIdx.x;
#pragma unroll
    for (int p = 0; p < 4; ++p) kis[p * 256 + t] = (int)idxf[b * 1024 + p * 256 + t];
    __syncthreads();
    float ls = 0.0f;
#pragma unroll 1
    for (int ci = 0; ci < 16; ++ci) {
        const int c = cg * 16 + ci;
        const size_t base = (size_t)b * 262144 + (size_t)c * 1024;
#pragma unroll
        for (int p = 0; p < 4; ++p) {
            const int hw = p * 256 + t;
            const float e  = emb[(size_t)kis[hw] * CC + c];
            const float zv = z[base + hw];
            out[base + hw] = e;
            const float df = e - zv;
            ls = fmaf(df, df, ls);
        }
    }
    red[t] = ls;
    __syncthreads();
    for (int s = 128; s > 0; s >>= 1) {
        if (t < s) red[t] += red[t + s];
        __syncthreads();
    }
    if (t == 0) atomicAdd(lossAcc, red[0]);
}

// ---------------- finalize loss ----------------
__global__ void k_loss(const float* __restrict__ lossAcc, float* __restrict__ outLoss) {
    if (threadIdx.x == 0) {
        float m = lossAcc[0] * (1.0f / 4194304.0f);
        outLoss[0] = m + 0.25f * m;
    }
}

extern "C" void kernel_launch(void* const* d_in, const int* in_sizes, int n_in,
                              void* d_out, int out_size, void* d_ws, size_t ws_size,
                              hipStream_t stream) {
    const float* z   = (const float*)d_in[0];
    const float* emb = (const float*)d_in[1];
    float* outf = (float*)d_out;
    float* wsf  = (float*)d_ws;

    float* lossAcc = wsf;
    float* znorm   = wsf + WS_ZNORM;
    float* enorm   = wsf + WS_ENORM;
    float* setmax  = wsf + WS_SETMAX;
    unsigned short* zb16 = (unsigned short*)(wsf + WS_ZB16);
    unsigned short* ebf  = (unsigned short*)(wsf + WS_EBF);

    float* zT = outf;   // d_out z_q region doubles as fp32 zT until k_gather overwrites

    k_prep_z<<<dim3(16, 4, 16), 256, 0, stream>>>(z, zT, zb16);
    k_prep_e<<<1024, 256, 0, stream>>>(emb, ebf);
    k_znorm<<<64, 256, 0, stream>>>(z, znorm, lossAcc);
    k_enorm<<<2048, 256, 0, stream>>>(emb, enorm);
    k_phase1<<<256, 512, 0, stream>>>(zb16, ebf, setmax);
    k_rescore<<<4096, 256, 0, stream>>>(zT, emb, zb16, ebf, znorm, enorm, setmax,
                                        outf + Z_OUT);
    k_gather<<<dim3(16, 16), 256, 0, stream>>>(z, emb, outf + Z_OUT, outf, lossAcc);
    k_loss<<<1, 64, 0, stream>>>(lossAcc, outf + Z_OUT + NPTS);
}

// Round 9
// 11341.753 us; speedup vs baseline: 1.2635x; 1.2635x over previous
//
#include <hip/hip_runtime.h>
#include <math.h>

// Problem constants
#define NB   16
#define CC   256
#define NPTS 16384       // 16*32*32
#define KK   8192
#define Z_OUT 4194304    // NPTS*CC
// d_out: [0,Z_OUT) z_q_out (BCHW), [Z_OUT,Z_OUT+NPTS) idx as float, [Z_OUT+NPTS] loss
// d_out scratch reuse: zT fp32[16384][256] fills the z_q region until k_gather
// overwrites it (rescore reads zT, writes idx — disjoint regions).

// ws layout (float-slot offsets)
#define WS_ZNORM 64
#define WS_ENORM 16448
#define WS_CCNT  24640                 // int[16384]
#define WS_CIDX  41024                 // int[16384][CAND_CAP]
#define WS_ZB16  1089600               // bf16[16384][256] (1,048,576 float-slots)
#define WS_EBF   2138176               // bf16[8192][256]  (524,288 float-slots)
#define CAND_CAP 64
#define MARGIN   4.0e-4f               // >= 2*bf16 dot err + d-quantum + enorm spread

typedef short v8s __attribute__((ext_vector_type(8)));
typedef float v4f __attribute__((ext_vector_type(4)));

__device__ __forceinline__ void gl_lds16(const void* g, void* l) {
    __builtin_amdgcn_global_load_lds((const __attribute__((address_space(1))) void*)g,
                                     (__attribute__((address_space(3))) void*)l, 16, 0, 0);
}
__device__ __forceinline__ unsigned short f2bf(float f) {   // RNE, finite inputs
    unsigned int u = __float_as_uint(f);
    return (unsigned short)((u + 0x7FFFu + ((u >> 16) & 1u)) >> 16);
}

// ---------------- P0: z BCHW fp32 -> zT[n][c] fp32 (d_out) + zb16[n][c] bf16 --------
__global__ void k_prep_z(const float* __restrict__ z, float* __restrict__ zT,
                         unsigned short* __restrict__ zb16) {
    __shared__ float ts[64][65];
    const int hw0 = blockIdx.x * 64, c0 = blockIdx.y * 64, b = blockIdx.z;
    const int tid = threadIdx.x;
#pragma unroll
    for (int p = 0; p < 4; ++p) {
        int u = p * 256 + tid;
        int ci = u >> 4, j4 = (u & 15) << 2;
        float4 v = *(const float4*)(z + (size_t)b * 262144 + (size_t)(c0 + ci) * 1024 + hw0 + j4);
        ts[ci][j4 + 0] = v.x; ts[ci][j4 + 1] = v.y; ts[ci][j4 + 2] = v.z; ts[ci][j4 + 3] = v.w;
    }
    __syncthreads();
#pragma unroll
    for (int p = 0; p < 4; ++p) {
        int u = p * 256 + tid;
        int hj = u >> 4, i4 = (u & 15) << 2;
        const size_t row = (size_t)(b * 1024 + hw0 + hj) * 256 + c0 + i4;
        float4 f = make_float4(ts[i4 + 0][hj], ts[i4 + 1][hj], ts[i4 + 2][hj], ts[i4 + 3][hj]);
        *(float4*)(zT + row) = f;
        *(ushort4*)(zb16 + row) = make_ushort4(f2bf(f.x), f2bf(f.y), f2bf(f.z), f2bf(f.w));
    }
}

// ---------------- P1: emb fp32 -> ebf[k][c] bf16 ----------------
__global__ void k_prep_e(const float* __restrict__ emb, unsigned short* __restrict__ ebf) {
    const int i = (blockIdx.x * 256 + threadIdx.x) * 8;
    float4 a = *(const float4*)(emb + i);
    float4 b = *(const float4*)(emb + i + 4);
    *(ushort4*)(ebf + i)     = make_ushort4(f2bf(a.x), f2bf(a.y), f2bf(a.z), f2bf(a.w));
    *(ushort4*)(ebf + i + 4) = make_ushort4(f2bf(b.x), f2bf(b.y), f2bf(b.z), f2bf(b.w));
}

// ---------------- znorm + zero loss + zero candCnt ----------------
__global__ void k_znorm(const float* __restrict__ z, float* __restrict__ znorm,
                        float* __restrict__ lossAcc, int* __restrict__ candCnt) {
    const int n  = blockIdx.x * 256 + threadIdx.x;
    const int b  = n >> 10, hw = n & 1023;
    const float* p = z + (size_t)b * 262144 + hw;
    float s = 0.0f;
#pragma unroll 8
    for (int c = 0; c < CC; ++c) {
        float v = p[(size_t)c * 1024];
        s = fmaf(v, v, s);
    }
    znorm[n] = s;
    candCnt[n] = 0;
    if (n == 0) lossAcc[0] = 0.0f;
}

// ---------------- enorm ----------------
__global__ void k_enorm(const float* __restrict__ emb, float* __restrict__ enorm) {
    const int w = threadIdx.x >> 6, lane = threadIdx.x & 63;
    const int k = blockIdx.x * 4 + w;
    float4 v = *(const float4*)(emb + (size_t)k * CC + lane * 4);
    float s = v.x * v.x + v.y * v.y + v.z * v.z + v.w * v.w;
    for (int off = 32; off > 0; off >>= 1) s += __shfl_down(s, off);
    if (lane == 0) enorm[k] = s;
}

// ---------------- Phase 1: bf16 MFMA + r5 block-tight runmax + global candidates ---
// 256 blocks x 512 thr (8 waves, 74.3 KB LDS -> 2 blk/CU). Block = 64 n, all 8192 k.
// Epilogue every 8th chunk: wavemax -> barrier -> block runmax merge -> barrier ->
// threshold push (r5-proven tight: ~4 cand/row). Candidates -> global atomics.
// mfma_f32_16x16x32_bf16 D: col(n)=lane&15, row(k)=(lane>>4)*4+reg (verified r5-8).
__global__ __launch_bounds__(512)
void k_phase1(const unsigned short* __restrict__ zb16, const unsigned short* __restrict__ ebf,
              int* __restrict__ candCnt, int* __restrict__ candI) {
    __shared__ short As[2][8][4][512];   // 64 KB  [buf][wave][ktile][lane*8]
    __shared__ short Bs[2][4][512];      // 8 KB   [buf][ntile][lane*8]
    __shared__ float wavemax[8][64];     // 2 KB
    __shared__ float runmax[64];         // 256 B

    const int tid  = threadIdx.x;
    const int lane = tid & 63;
    const int w    = tid >> 6;
    const int nb   = blockIdx.x << 6;
    const int m16  = lane & 15, q = lane >> 4;

    if (tid < 64) runmax[tid] = -__builtin_inff();

    auto stage = [&](int t) {
        const int s = t >> 3, c0 = (t & 7) << 5, buf = t & 1;
        const int kbase = (w << 10) + (s << 6);
#pragma unroll
        for (int kt = 0; kt < 4; ++kt) {
            const unsigned short* g = ebf + (size_t)(kbase + (kt << 4) + m16) * 256 + c0 + q * 8;
            gl_lds16(g, &As[buf][w][kt][lane * 8]);
        }
        if (w < 4) {
            const unsigned short* g = zb16 + (size_t)(nb + (w << 4) + m16) * 256 + c0 + q * 8;
            gl_lds16(g, &Bs[buf][w][lane * 8]);
        }
    };

    stage(0);

    v4f acc[16];
#pragma unroll
    for (int i = 0; i < 16; ++i) acc[i] = (v4f){0.f, 0.f, 0.f, 0.f};

#pragma unroll 1
    for (int t = 0; t < 128; ++t) {
        __syncthreads();
        if (t + 1 < 128) stage(t + 1);
        const int buf = t & 1;
        v8s af[4], bf[4];
#pragma unroll
        for (int kt = 0; kt < 4; ++kt) af[kt] = *(const v8s*)&As[buf][w][kt][lane * 8];
#pragma unroll
        for (int nt = 0; nt < 4; ++nt) bf[nt] = *(const v8s*)&Bs[buf][nt][lane * 8];
#pragma unroll
        for (int kt = 0; kt < 4; ++kt)
#pragma unroll
            for (int nt = 0; nt < 4; ++nt)
                acc[kt * 4 + nt] = __builtin_amdgcn_mfma_f32_16x16x32_bf16(
                    af[kt], bf[nt], acc[kt * 4 + nt], 0, 0, 0);

        if ((t & 7) == 7) {   // end of a 64-k set: r5 epilogue
            const int s = t >> 3;
#pragma unroll
            for (int nt = 0; nt < 4; ++nt) {
                float m = acc[nt][0];
#pragma unroll
                for (int kt = 0; kt < 4; ++kt)
#pragma unroll
                    for (int r = 0; r < 4; ++r) m = fmaxf(m, acc[kt * 4 + nt][r]);
                m = fmaxf(m, __shfl_xor(m, 16));
                m = fmaxf(m, __shfl_xor(m, 32));
                if (lane < 16) wavemax[w][nt * 16 + lane] = m;
            }
            __syncthreads();
            if (tid < 64) {
                float r = runmax[tid];
#pragma unroll
                for (int ww = 0; ww < 8; ++ww) r = fmaxf(r, wavemax[ww][tid]);
                runmax[tid] = r;
            }
            __syncthreads();
#pragma unroll
            for (int nt = 0; nt < 4; ++nt) {
                const int nl = nt * 16 + m16;
                const float thr = runmax[nl] - MARGIN;
                const int n = nb + nl;
#pragma unroll
                for (int kt = 0; kt < 4; ++kt)
#pragma unroll
                    for (int r = 0; r < 4; ++r) {
                        if (acc[kt * 4 + nt][r] >= thr) {
                            int k = (w << 10) + (s << 6) + (kt << 4) + q * 4 + r;
                            int pos = atomicAdd(&candCnt[n], 1);
                            if (pos < CAND_CAP) candI[(size_t)n * CAND_CAP + pos] = k;
                        }
                    }
            }
#pragma unroll
            for (int i = 0; i < 16; ++i) acc[i] = (v4f){0.f, 0.f, 0.f, 0.f};
        }
    }
}

// ---------------- Phase 2: exact fp32 rescore (chain identical to rounds 4-8) ------
// One wave per row (4096 blocks x 256 thr); one candidate per lane; float4 reads.
__global__ __launch_bounds__(256)
void k_rescore(const float* __restrict__ zT, const float* __restrict__ emb,
               const float* __restrict__ znorm, const float* __restrict__ enorm,
               const int* __restrict__ candCnt, const int* __restrict__ candI,
               float* __restrict__ idx_out) {
    const int lane = threadIdx.x & 63;
    const int n    = blockIdx.x * 4 + (threadIdx.x >> 6);
    const float* zp = zT + (size_t)n * CC;
    const float zn = znorm[n];
    const int cnt = candCnt[n];
    float bd = __builtin_inff();
    int   bk = 0x7fffffff;
    if (cnt <= CAND_CAP) {
        if (lane < cnt) {                      // cnt <= 64: one candidate per lane
            const int k = candI[(size_t)n * CAND_CAP + lane];
            const float* ep = emb + (size_t)k * CC;
            float acc = 0.0f;
#pragma unroll 8
            for (int c4 = 0; c4 < CC / 4; ++c4) {
                const float4 zv = *(const float4*)(zp + c4 * 4);
                const float4 ev = *(const float4*)(ep + c4 * 4);
                acc = fmaf(zv.x, ev.x, acc);
                acc = fmaf(zv.y, ev.y, acc);
                acc = fmaf(zv.z, ev.z, acc);
                acc = fmaf(zv.w, ev.w, acc);
            }
            const float tt = zn + enorm[k];
            bd = tt - (acc + acc);
            bk = k;
        }
    } else {
        // overflow fallback (rare with tight threshold): exact full scan, same chain
#pragma unroll 1
        for (int kb = 0; kb < 128; ++kb) {
            const int k = kb * 64 + lane;
            const float* ep = emb + (size_t)k * CC;
            float acc = 0.0f;
#pragma unroll 8
            for (int c4 = 0; c4 < CC / 4; ++c4) {
                const float4 zv = *(const float4*)(zp + c4 * 4);
                const float4 ev = *(const float4*)(ep + c4 * 4);
                acc = fmaf(zv.x, ev.x, acc);
                acc = fmaf(zv.y, ev.y, acc);
                acc = fmaf(zv.z, ev.z, acc);
                acc = fmaf(zv.w, ev.w, acc);
            }
            const float tt = zn + enorm[k];
            const float d = tt - (acc + acc);
            if (d < bd) { bd = d; bk = k; }    // ascending k per lane
        }
    }
    // cross-lane min with smaller-k tie-break
#pragma unroll
    for (int off = 32; off > 0; off >>= 1) {
        const float od = __shfl_down(bd, off);
        const int   ok = __shfl_down(bk, off);
        if (od < bd || (od == bd && ok < bk)) { bd = od; bk = ok; }
    }
    if (lane == 0) idx_out[n] = (float)bk;
}

// ---------------- gather z_q (BCHW, coalesced) + loss partials ----------------
__global__ void k_gather(const float* __restrict__ z, const float* __restrict__ emb,
                         const float* __restrict__ idxf, float* __restrict__ out,
                         float* __restrict__ lossAcc) {
    __shared__ int   kis[1024];
    __shared__ float red[256];
    const int b = blockIdx.x, cg = blockIdx.y;   // 16 x 16
    const int t = threadIdx.x;
#pragma unroll
    for (int p = 0; p < 4; ++p) kis[p * 256 + t] = (int)idxf[b * 1024 + p * 256 + t];
    __syncthreads();
    float ls = 0.0f;
#pragma unroll 1
    for (int ci = 0; ci < 16; ++ci) {
        const int c = cg * 16 + ci;
        const size_t base = (size_t)b * 262144 + (size_t)c * 1024;
#pragma unroll
        for (int p = 0; p < 4; ++p) {
            const int hw = p * 256 + t;
            const float e  = emb[(size_t)kis[hw] * CC + c];
            const float zv = z[base + hw];
            out[base + hw] = e;
            const float df = e - zv;
            ls = fmaf(df, df, ls);
        }
    }
    red[t] = ls;
    __syncthreads();
    for (int s = 128; s > 0; s >>= 1) {
        if (t < s) red[t] += red[t + s];
        __syncthreads();
    }
    if (t == 0) atomicAdd(lossAcc, red[0]);
}

// ---------------- finalize loss ----------------
__global__ void k_loss(const float* __restrict__ lossAcc, float* __restrict__ outLoss) {
    if (threadIdx.x == 0) {
        float m = lossAcc[0] * (1.0f / 4194304.0f);
        outLoss[0] = m + 0.25f * m;
    }
}

extern "C" void kernel_launch(void* const* d_in, const int* in_sizes, int n_in,
                              void* d_out, int out_size, void* d_ws, size_t ws_size,
                              hipStream_t stream) {
    const float* z   = (const float*)d_in[0];
    const float* emb = (const float*)d_in[1];
    float* outf = (float*)d_out;
    float* wsf  = (float*)d_ws;

    float* lossAcc = wsf;
    float* znorm   = wsf + WS_ZNORM;
    float* enorm   = wsf + WS_ENORM;
    int*   candCnt = (int*)(wsf + WS_CCNT);
    int*   candI   = (int*)(wsf + WS_CIDX);
    unsigned short* zb16 = (unsigned short*)(wsf + WS_ZB16);
    unsigned short* ebf  = (unsigned short*)(wsf + WS_EBF);

    float* zT = outf;   // d_out z_q region doubles as fp32 zT until k_gather overwrites

    k_prep_z<<<dim3(16, 4, 16), 256, 0, stream>>>(z, zT, zb16);
    k_prep_e<<<1024, 256, 0, stream>>>(emb, ebf);
    k_znorm<<<64, 256, 0, stream>>>(z, znorm, lossAcc, candCnt);
    k_enorm<<<2048, 256, 0, stream>>>(emb, enorm);
    k_phase1<<<256, 512, 0, stream>>>(zb16, ebf, candCnt, candI);
    k_rescore<<<4096, 256, 0, stream>>>(zT, emb, znorm, enorm, candCnt, candI, outf + Z_OUT);
    k_gather<<<dim3(16, 16), 256, 0, stream>>>(z, emb, outf + Z_OUT, outf, lossAcc);
    k_loss<<<1, 64, 0, stream>>>(lossAcc, outf + Z_OUT + NPTS);
}

// Round 10
// 1052.186 us; speedup vs baseline: 13.6198x; 10.7792x over previous
//
#include <hip/hip_runtime.h>
#include <math.h>

// Problem constants
#define NB   16
#define CC   256
#define NPTS 16384       // 16*32*32
#define KK   8192
#define Z_OUT 4194304    // NPTS*CC
// d_out: [0,Z_OUT) z_q_out (BCHW), [Z_OUT,Z_OUT+NPTS) idx as float, [Z_OUT+NPTS] loss
// d_out scratch reuse: zT fp32[16384][256] fills the z_q region until k_gather
// overwrites it (rescore reads zT, writes idx — disjoint regions).

// ws layout (float-slot offsets) — r7-verified, NO overlaps:
//   lossAcc  [0]
//   znorm    [64 .. 16448)           float[16384]
//   enorm    [16448 .. 24640)        float[8192]
//   candCnt  [24640 .. 41024)        int[16384]
//   candI    [41024 .. 565312)       int[16384][32]
//   zb16     [565312 .. 2662464)     bf16[16384][256] = 2,097,152 float-slots
//   ebf      [2662464 .. 3711040)    bf16[8192][256]  = 1,048,576 float-slots
#define WS_ZNORM 64
#define WS_ENORM 16448
#define WS_CCNT  24640
#define WS_CIDX  41024
#define WS_ZB16  565312
#define WS_EBF   2662464
#define CAND_CAP 32
#define MARGIN   4.0e-4f               // >= 2*bf16 dot err + d-quantum + enorm spread

typedef short v8s __attribute__((ext_vector_type(8)));
typedef float v4f __attribute__((ext_vector_type(4)));

__device__ __forceinline__ void gl_lds16(const void* g, void* l) {
    __builtin_amdgcn_global_load_lds((const __attribute__((address_space(1))) void*)g,
                                     (__attribute__((address_space(3))) void*)l, 16, 0, 0);
}
__device__ __forceinline__ unsigned short f2bf(float f) {   // RNE, finite inputs
    unsigned int u = __float_as_uint(f);
    return (unsigned short)((u + 0x7FFFu + ((u >> 16) & 1u)) >> 16);
}

// ---------------- P0: z BCHW fp32 -> zT[n][c] fp32 (d_out) + zb16[n][c] bf16 --------
__global__ void k_prep_z(const float* __restrict__ z, float* __restrict__ zT,
                         unsigned short* __restrict__ zb16) {
    __shared__ float ts[64][65];
    const int hw0 = blockIdx.x * 64, c0 = blockIdx.y * 64, b = blockIdx.z;
    const int tid = threadIdx.x;
#pragma unroll
    for (int p = 0; p < 4; ++p) {
        int u = p * 256 + tid;
        int ci = u >> 4, j4 = (u & 15) << 2;
        float4 v = *(const float4*)(z + (size_t)b * 262144 + (size_t)(c0 + ci) * 1024 + hw0 + j4);
        ts[ci][j4 + 0] = v.x; ts[ci][j4 + 1] = v.y; ts[ci][j4 + 2] = v.z; ts[ci][j4 + 3] = v.w;
    }
    __syncthreads();
#pragma unroll
    for (int p = 0; p < 4; ++p) {
        int u = p * 256 + tid;
        int hj = u >> 4, i4 = (u & 15) << 2;
        const size_t row = (size_t)(b * 1024 + hw0 + hj) * 256 + c0 + i4;
        float4 f = make_float4(ts[i4 + 0][hj], ts[i4 + 1][hj], ts[i4 + 2][hj], ts[i4 + 3][hj]);
        *(float4*)(zT + row) = f;
        *(ushort4*)(zb16 + row) = make_ushort4(f2bf(f.x), f2bf(f.y), f2bf(f.z), f2bf(f.w));
    }
}

// ---------------- P1: emb fp32 -> ebf[k][c] bf16 ----------------
__global__ void k_prep_e(const float* __restrict__ emb, unsigned short* __restrict__ ebf) {
    const int i = (blockIdx.x * 256 + threadIdx.x) * 8;
    float4 a = *(const float4*)(emb + i);
    float4 b = *(const float4*)(emb + i + 4);
    *(ushort4*)(ebf + i)     = make_ushort4(f2bf(a.x), f2bf(a.y), f2bf(a.z), f2bf(a.w));
    *(ushort4*)(ebf + i + 4) = make_ushort4(f2bf(b.x), f2bf(b.y), f2bf(b.z), f2bf(b.w));
}

// ---------------- znorm + zero loss + zero candCnt ----------------
__global__ void k_znorm(const float* __restrict__ z, float* __restrict__ znorm,
                        float* __restrict__ lossAcc, int* __restrict__ candCnt) {
    const int n  = blockIdx.x * 256 + threadIdx.x;
    const int b  = n >> 10, hw = n & 1023;
    const float* p = z + (size_t)b * 262144 + hw;
    float s = 0.0f;
#pragma unroll 8
    for (int c = 0; c < CC; ++c) {
        float v = p[(size_t)c * 1024];
        s = fmaf(v, v, s);
    }
    znorm[n] = s;
    candCnt[n] = 0;
    if (n == 0) lossAcc[0] = 0.0f;
}

// ---------------- enorm ----------------
__global__ void k_enorm(const float* __restrict__ emb, float* __restrict__ enorm) {
    const int w = threadIdx.x >> 6, lane = threadIdx.x & 63;
    const int k = blockIdx.x * 4 + w;
    float4 v = *(const float4*)(emb + (size_t)k * CC + lane * 4);
    float s = v.x * v.x + v.y * v.y + v.z * v.z + v.w * v.w;
    for (int off = 32; off > 0; off >>= 1) s += __shfl_down(s, off);
    if (lane == 0) enorm[k] = s;
}

// ---------------- Phase 1: bf16 MFMA + r5 block-tight runmax + global candidates ---
// 256 blocks x 512 thr (8 waves, 74.3 KB LDS -> 2 blk/CU). Block = 64 n, all 8192 k.
// Epilogue every 8th chunk: wavemax -> barrier -> block runmax merge -> barrier ->
// threshold push (r5-proven tight: ~4 cand/row). Candidates -> global atomics.
// mfma_f32_16x16x32_bf16 D: col(n)=lane&15, row(k)=(lane>>4)*4+reg (verified r5-9).
__global__ __launch_bounds__(512)
void k_phase1(const unsigned short* __restrict__ zb16, const unsigned short* __restrict__ ebf,
              int* __restrict__ candCnt, int* __restrict__ candI) {
    __shared__ short As[2][8][4][512];   // 64 KB  [buf][wave][ktile][lane*8]
    __shared__ short Bs[2][4][512];      // 8 KB   [buf][ntile][lane*8]
    __shared__ float wavemax[8][64];     // 2 KB
    __shared__ float runmax[64];         // 256 B

    const int tid  = threadIdx.x;
    const int lane = tid & 63;
    const int w    = tid >> 6;
    const int nb   = blockIdx.x << 6;
    const int m16  = lane & 15, q = lane >> 4;

    if (tid < 64) runmax[tid] = -__builtin_inff();

    auto stage = [&](int t) {
        const int s = t >> 3, c0 = (t & 7) << 5, buf = t & 1;
        const int kbase = (w << 10) + (s << 6);
#pragma unroll
        for (int kt = 0; kt < 4; ++kt) {
            const unsigned short* g = ebf + (size_t)(kbase + (kt << 4) + m16) * 256 + c0 + q * 8;
            gl_lds16(g, &As[buf][w][kt][lane * 8]);
        }
        if (w < 4) {
            const unsigned short* g = zb16 + (size_t)(nb + (w << 4) + m16) * 256 + c0 + q * 8;
            gl_lds16(g, &Bs[buf][w][lane * 8]);
        }
    };

    stage(0);

    v4f acc[16];
#pragma unroll
    for (int i = 0; i < 16; ++i) acc[i] = (v4f){0.f, 0.f, 0.f, 0.f};

#pragma unroll 1
    for (int t = 0; t < 128; ++t) {
        __syncthreads();
        if (t + 1 < 128) stage(t + 1);
        const int buf = t & 1;
        v8s af[4], bf[4];
#pragma unroll
        for (int kt = 0; kt < 4; ++kt) af[kt] = *(const v8s*)&As[buf][w][kt][lane * 8];
#pragma unroll
        for (int nt = 0; nt < 4; ++nt) bf[nt] = *(const v8s*)&Bs[buf][nt][lane * 8];
#pragma unroll
        for (int kt = 0; kt < 4; ++kt)
#pragma unroll
            for (int nt = 0; nt < 4; ++nt)
                acc[kt * 4 + nt] = __builtin_amdgcn_mfma_f32_16x16x32_bf16(
                    af[kt], bf[nt], acc[kt * 4 + nt], 0, 0, 0);

        if ((t & 7) == 7) {   // end of a 64-k set: r5 epilogue
            const int s = t >> 3;
#pragma unroll
            for (int nt = 0; nt < 4; ++nt) {
                float m = acc[nt][0];
#pragma unroll
                for (int kt = 0; kt < 4; ++kt)
#pragma unroll
                    for (int r = 0; r < 4; ++r) m = fmaxf(m, acc[kt * 4 + nt][r]);
                m = fmaxf(m, __shfl_xor(m, 16));
                m = fmaxf(m, __shfl_xor(m, 32));
                if (lane < 16) wavemax[w][nt * 16 + lane] = m;
            }
            __syncthreads();
            if (tid < 64) {
                float r = runmax[tid];
#pragma unroll
                for (int ww = 0; ww < 8; ++ww) r = fmaxf(r, wavemax[ww][tid]);
                runmax[tid] = r;
            }
            __syncthreads();
#pragma unroll
            for (int nt = 0; nt < 4; ++nt) {
                const int nl = nt * 16 + m16;
                const float thr = runmax[nl] - MARGIN;
                const int n = nb + nl;
#pragma unroll
                for (int kt = 0; kt < 4; ++kt)
#pragma unroll
                    for (int r = 0; r < 4; ++r) {
                        if (acc[kt * 4 + nt][r] >= thr) {
                            int k = (w << 10) + (s << 6) + (kt << 4) + q * 4 + r;
                            int pos = atomicAdd(&candCnt[n], 1);
                            if (pos < CAND_CAP) candI[(size_t)n * CAND_CAP + pos] = k;
                        }
                    }
            }
#pragma unroll
            for (int i = 0; i < 16; ++i) acc[i] = (v4f){0.f, 0.f, 0.f, 0.f};
        }
    }
}

// ---------------- Phase 2: exact fp32 rescore (chain identical to rounds 4-9) ------
// One wave per row (4096 blocks x 256 thr); one candidate per lane; float4 reads.
__global__ __launch_bounds__(256)
void k_rescore(const float* __restrict__ zT, const float* __restrict__ emb,
               const float* __restrict__ znorm, const float* __restrict__ enorm,
               const int* __restrict__ candCnt, const int* __restrict__ candI,
               float* __restrict__ idx_out) {
    const int lane = threadIdx.x & 63;
    const int n    = blockIdx.x * 4 + (threadIdx.x >> 6);
    const float* zp = zT + (size_t)n * CC;
    const float zn = znorm[n];
    const int cnt = candCnt[n];
    float bd = __builtin_inff();
    int   bk = 0x7fffffff;
    if (cnt <= CAND_CAP) {
        if (lane < cnt) {                      // cnt <= 32: one candidate per lane
            const int k = candI[(size_t)n * CAND_CAP + lane];
            const float* ep = emb + (size_t)k * CC;
            float acc = 0.0f;
#pragma unroll 8
            for (int c4 = 0; c4 < CC / 4; ++c4) {
                const float4 zv = *(const float4*)(zp + c4 * 4);
                const float4 ev = *(const float4*)(ep + c4 * 4);
                acc = fmaf(zv.x, ev.x, acc);
                acc = fmaf(zv.y, ev.y, acc);
                acc = fmaf(zv.z, ev.z, acc);
                acc = fmaf(zv.w, ev.w, acc);
            }
            const float tt = zn + enorm[k];
            bd = tt - (acc + acc);
            bk = k;
        }
    } else {
        // overflow fallback (rare with tight threshold): exact full scan, same chain
#pragma unroll 1
        for (int kb = 0; kb < 128; ++kb) {
            const int k = kb * 64 + lane;
            const float* ep = emb + (size_t)k * CC;
            float acc = 0.0f;
#pragma unroll 8
            for (int c4 = 0; c4 < CC / 4; ++c4) {
                const float4 zv = *(const float4*)(zp + c4 * 4);
                const float4 ev = *(const float4*)(ep + c4 * 4);
                acc = fmaf(zv.x, ev.x, acc);
                acc = fmaf(zv.y, ev.y, acc);
                acc = fmaf(zv.z, ev.z, acc);
                acc = fmaf(zv.w, ev.w, acc);
            }
            const float tt = zn + enorm[k];
            const float d = tt - (acc + acc);
            if (d < bd) { bd = d; bk = k; }    // ascending k per lane
        }
    }
    // cross-lane min with smaller-k tie-break
#pragma unroll
    for (int off = 32; off > 0; off >>= 1) {
        const float od = __shfl_down(bd, off);
        const int   ok = __shfl_down(bk, off);
        if (od < bd || (od == bd && ok < bk)) { bd = od; bk = ok; }
    }
    if (lane == 0) idx_out[n] = (float)bk;
}

// ---------------- gather z_q (BCHW, coalesced) + loss partials ----------------
__global__ void k_gather(const float* __restrict__ z, const float* __restrict__ emb,
                         const float* __restrict__ idxf, float* __restrict__ out,
                         float* __restrict__ lossAcc) {
    __shared__ int   kis[1024];
    __shared__ float red[256];
    const int b = blockIdx.x, cg = blockIdx.y;   // 16 x 16
    const int t = threadIdx.x;
#pragma unroll
    for (int p = 0; p < 4; ++p) kis[p * 256 + t] = (int)idxf[b * 1024 + p * 256 + t];
    __syncthreads();
    float ls = 0.0f;
#pragma unroll 1
    for (int ci = 0; ci < 16; ++ci) {
        const int c = cg * 16 + ci;
        const size_t base = (size_t)b * 262144 + (size_t)c * 1024;
#pragma unroll
        for (int p = 0; p < 4; ++p) {
            const int hw = p * 256 + t;
            const float e  = emb[(size_t)kis[hw] * CC + c];
            const float zv = z[base + hw];
            out[base + hw] = e;
            const float df = e - zv;
            ls = fmaf(df, df, ls);
        }
    }
    red[t] = ls;
    __syncthreads();
    for (int s = 128; s > 0; s >>= 1) {
        if (t < s) red[t] += red[t + s];
        __syncthreads();
    }
    if (t == 0) atomicAdd(lossAcc, red[0]);
}

// ---------------- finalize loss ----------------
__global__ void k_loss(const float* __restrict__ lossAcc, float* __restrict__ outLoss) {
    if (threadIdx.x == 0) {
        float m = lossAcc[0] * (1.0f / 4194304.0f);
        outLoss[0] = m + 0.25f * m;
    }
}

extern "C" void kernel_launch(void* const* d_in, const int* in_sizes, int n_in,
                              void* d_out, int out_size, void* d_ws, size_t ws_size,
                              hipStream_t stream) {
    const float* z   = (const float*)d_in[0];
    const float* emb = (const float*)d_in[1];
    float* outf = (float*)d_out;
    float* wsf  = (float*)d_ws;

    float* lossAcc = wsf;
    float* znorm   = wsf + WS_ZNORM;
    float* enorm   = wsf + WS_ENORM;
    int*   candCnt = (int*)(wsf + WS_CCNT);
    int*   candI   = (int*)(wsf + WS_CIDX);
    unsigned short* zb16 = (unsigned short*)(wsf + WS_ZB16);
    unsigned short* ebf  = (unsigned short*)(wsf + WS_EBF);

    float* zT = outf;   // d_out z_q region doubles as fp32 zT until k_gather overwrites

    k_prep_z<<<dim3(16, 4, 16), 256, 0, stream>>>(z, zT, zb16);
    k_prep_e<<<1024, 256, 0, stream>>>(emb, ebf);
    k_znorm<<<64, 256, 0, stream>>>(z, znorm, lossAcc, candCnt);
    k_enorm<<<2048, 256, 0, stream>>>(emb, enorm);
    k_phase1<<<256, 512, 0, stream>>>(zb16, ebf, candCnt, candI);
    k_rescore<<<4096, 256, 0, stream>>>(zT, emb, znorm, enorm, candCnt, candI, outf + Z_OUT);
    k_gather<<<dim3(16, 16), 256, 0, stream>>>(z, emb, outf + Z_OUT, outf, lossAcc);
    k_loss<<<1, 64, 0, stream>>>(lossAcc, outf + Z_OUT + NPTS);
}